// Round 16
// baseline (1103.699 us; speedup 1.0000x reference)
//
#include <hip/hip_runtime.h>

#define NN 50000
#define HID 128
#define IN_C 100
#define OUT_C 40

// ---------------------------------------------------------------------------
__global__ __launch_bounds__(256)
void hist_kernel(const int* __restrict__ dst, int* __restrict__ deg, int E) {
    int e = blockIdx.x * 256 + threadIdx.x;
    if (e < E) atomicAdd(&deg[dst[e]], 1);
}

// ---------------------------------------------------------------------------
__global__ __launch_bounds__(256)
void chunk_sum_kernel(const int* __restrict__ deg, int* __restrict__ chunk_sums, int N) {
    __shared__ int s[256];
    const int t = threadIdx.x;
    const int i = blockIdx.x * 256 + t;
    s[t] = (i < N) ? deg[i] : 0;
    __syncthreads();
    for (int o = 128; o; o >>= 1) { if (t < o) s[t] += s[t + o]; __syncthreads(); }
    if (t == 0) chunk_sums[blockIdx.x] = s[0];
}

__global__ __launch_bounds__(256)
void chunk_scan_kernel(int* __restrict__ chunk_sums, int M) {
    __shared__ int s[256];
    const int t = threadIdx.x;
    int v = (t < M) ? chunk_sums[t] : 0;
    s[t] = v;
    __syncthreads();
    for (int o = 1; o < 256; o <<= 1) {
        int x = (t >= o) ? s[t - o] : 0;
        __syncthreads();
        s[t] += x;
        __syncthreads();
    }
    if (t < M) chunk_sums[t] = s[t] - v;   // exclusive
}

__global__ __launch_bounds__(256)
void chunk_apply_kernel(const int* __restrict__ deg, const int* __restrict__ chunk_sums,
                        int* __restrict__ row_start, int* __restrict__ cursor, int N) {
    __shared__ int s[256];
    const int t = threadIdx.x;
    const int i = blockIdx.x * 256 + t;
    int v = (i < N) ? deg[i] : 0;
    s[t] = v;
    __syncthreads();
    for (int o = 1; o < 256; o <<= 1) {
        int x = (t >= o) ? s[t - o] : 0;
        __syncthreads();
        s[t] += x;
        __syncthreads();
    }
    if (i < N) {
        int ex = chunk_sums[blockIdx.x] + s[t] - v;
        row_start[i] = ex;
        cursor[i] = ex;
        if (i == N - 1) row_start[N] = ex + v;
    }
}

// ---------------------------------------------------------------------------
__global__ __launch_bounds__(256)
void scatter_kernel(const int* __restrict__ src, const int* __restrict__ dst,
                    int* __restrict__ cursor, int* __restrict__ csr_src, int E) {
    int e = blockIdx.x * 256 + threadIdx.x;
    if (e < E) {
        int pos = atomicAdd(&cursor[dst[e]], 1);
        csr_src[pos] = src[e];
    }
}

// ---------------------------------------------------------------------------
__device__ __forceinline__ double2 ld2(const double* p) {
    return *(const double2*)(p);
}
__device__ __forceinline__ double2 ld2(const float* p) {
    float2 v = *(const float2*)(p);
    return make_double2((double)v.x, (double)v.y);
}

// ---------------------------------------------------------------------------
// PURE gather kernel: wave-per-node, NO LDS, max occupancy (up to 32 waves/CU)
// so the latency-bound CSR gather gets 4x the in-flight requests of the fused
// version. Arithmetic is bit-identical to r15's phase A (same 4-deep unroll,
// same pairwise combine, f64). Output stride is HID (=128) always, into the
// layer's OUTPUT h-region (safe: mlp blocks read their own agg rows into LDS
// before overwriting those same rows).
template<int K, typename TIN>
__global__ __launch_bounds__(256, 8)
void agg_kernel(const TIN* __restrict__ h_in, const int* __restrict__ row_start,
                const int* __restrict__ csr_src, double* __restrict__ aggout) {
    const int t = threadIdx.x;
    const int w = t >> 6, lane = t & 63;
    const int n = blockIdx.x * 4 + w;
    const int f0 = 2 * lane;
    if (f0 >= K) return;
    const int r0 = row_start[n], r1 = row_start[n + 1];
    double s0 = 0, s1 = 0, s2 = 0, s3 = 0, s4 = 0, s5 = 0, s6 = 0, s7 = 0;
    int i = r0;
    for (; i + 3 < r1; i += 4) {
        const double2 v0 = ld2(h_in + (size_t)csr_src[i] * K + f0);
        const double2 v1 = ld2(h_in + (size_t)csr_src[i + 1] * K + f0);
        const double2 v2 = ld2(h_in + (size_t)csr_src[i + 2] * K + f0);
        const double2 v3 = ld2(h_in + (size_t)csr_src[i + 3] * K + f0);
        s0 += v0.x; s1 += v0.y; s2 += v1.x; s3 += v1.y;
        s4 += v2.x; s5 += v2.y; s6 += v3.x; s7 += v3.y;
    }
    for (; i < r1; ++i) {
        const double2 v = ld2(h_in + (size_t)csr_src[i] * K + f0);
        s0 += v.x; s1 += v.y;
    }
    const int deg = r1 - r0;
    const double dd = (double)(deg > 1 ? deg : 1);
    aggout[(size_t)n * HID + f0]     = ((s0 + s2) + (s4 + s6)) / dd;
    aggout[(size_t)n * HID + f0 + 1] = ((s1 + s3) + (s5 + s7)) / dd;
}

// ---------------------------------------------------------------------------
// mlp+rvq kernel: r15's layer_fused minus the gather phase. Reads agg rows
// (coalesced f64) + root rows, then GEMM + BN/ReLU + RVQ [+ LAST linear head].
// Numerics recipe (DO NOT CHANGE): f64 h end-to-end; all accumulation f64;
// d2 = fl32(fl32(rr32 - 2*rc32) + cc32); argmin = first-min.
// NOTE: agg rows live in the same buffer as h_out; each block reads its own
// 8 rows into LDS (phase A'), barriers, then overwrites them in phase C.
template<int K, bool HAS_BN, bool LAST, typename TIN>
__global__ __launch_bounds__(512, 6)
void mlp_rvq(const TIN* __restrict__ h_in, const double* __restrict__ aggin,
             const float* __restrict__ Wa, const float* __restrict__ Wr,
             const float* __restrict__ b,
             const float* __restrict__ gamma, const float* __restrict__ beta,
             const float* __restrict__ mean, const float* __restrict__ var,
             const float* __restrict__ cb,       // [3*16*128] this layer
             double* __restrict__ h_out,         // may alias aggin (see note)
             float* __restrict__ ids_out, int id_col0,
             double* __restrict__ loss_part,
             const float* __restrict__ lin_W, const float* __restrict__ lin_b,
             float* __restrict__ out) {
    __shared__ double s_agg[8][HID];   // phase A': agg rows; phase C/D: h rows
    __shared__ double s_h[8][HID];     // root rows; LAST: output rows for head
    __shared__ float s_cb[3 * 16 * 129];   // padded stride 129
    __shared__ float s_cc32[3][16];
    __shared__ double s_ws[8];
    const int t = threadIdx.x;
    const int w = t >> 6, lane = t & 63;
    const int n0 = blockIdx.x * 8;

    // ---- codebook -> LDS (padded) ----
    for (int idx = t; idx < 3 * 16 * 128; idx += 512)
        s_cb[(idx >> 7) * 129 + (idx & 127)] = cb[idx];

    // ---- phase A': load agg rows (stride HID) + root rows (stride K) ----
    {
        const int n = n0 + w;
        const int f0 = 2 * lane;
        if (f0 < K) {
            const double2 a = *(const double2*)(aggin + (size_t)n * HID + f0);
            const double2 root = ld2(h_in + (size_t)n * K + f0);
            s_agg[w][f0]     = a.x;
            s_agg[w][f0 + 1] = a.y;
            s_h[w][f0]     = root.x;
            s_h[w][f0 + 1] = root.y;
        }
    }
    __syncthreads();

    // ---- phase B: GEMM, direct f32 weight loads, f64 accumulate ----
    const int col = t & 127;
    const int p4 = t >> 7;      // 0..3; nodes p4 and p4+4
    double accA = (double)b[col];
    double accB = accA;
#pragma unroll 4
    for (int k = 0; k < K; ++k) {
        const double wa = (double)Wa[(size_t)k * HID + col];
        const double wr = (double)Wr[(size_t)k * HID + col];
        accA += s_agg[p4][k] * wa + s_h[p4][k] * wr;
        accB += s_agg[p4 + 4][k] * wa + s_h[p4 + 4][k] * wr;
    }
    __syncthreads();   // all GEMM reads of s_agg/s_h complete

    // ---- phase C: BN(f64)+ReLU, write f64 h (not LAST), stash rows ----
    {
        double vA = accA, vB = accB;
        if (HAS_BN) {
            const double scale = (double)gamma[col] / sqrt((double)var[col] + 1e-5);
            const double shift = (double)beta[col] - (double)mean[col] * scale;
            vA = vA * scale + shift; vA = vA > 0.0 ? vA : 0.0;
            vB = vB * scale + shift; vB = vB > 0.0 ? vB : 0.0;
        }
        if (!LAST) {   // LAST layer's h_out is dead (head uses LDS copy)
            h_out[(size_t)(n0 + p4) * HID + col] = vA;
            h_out[(size_t)(n0 + p4 + 4) * HID + col] = vB;
        }
        s_agg[p4][col] = vA;
        s_agg[p4 + 4][col] = vB;
        if (LAST) {                      // keep output rows for the linear head
            s_h[p4][col] = vA;
            s_h[p4 + 4][col] = vB;
        }
    }
    if (t < 48) {
        const float* c = &s_cb[t * 129];
        double s = 0.0;
        for (int j = 0; j < 128; j++) { double cj = (double)c[j]; s += cj * cj; }
        s_cc32[t >> 4][t & 15] = (float)s;
    }
    __syncthreads();

    // ---- phase D: RVQ, wave w on its node (wave-lockstep, no barriers) ----
    {
        double* res = &s_agg[w][0];
        const int n = n0 + w;
        const int k = lane & 15, q = lane >> 4;

        for (int g = 0; g < 3; ++g) {
            // rr = ||res||^2 (f64 butterfly)
            double r0 = res[lane], r1 = res[lane + 64];
            double pr = r0 * r0 + r1 * r1;
            pr += __shfl_xor(pr, 1, 64);
            pr += __shfl_xor(pr, 2, 64);
            pr += __shfl_xor(pr, 4, 64);
            pr += __shfl_xor(pr, 8, 64);
            pr += __shfl_xor(pr, 16, 64);
            pr += __shfl_xor(pr, 32, 64);
            const float rr32 = (float)pr;

            // dot(res, c_k): lane (k,q) does quarter q with q-rotation
            const float* c = &s_cb[(g * 16 + k) * 129];
            double dot = 0.0;
#pragma unroll
            for (int j2 = 0; j2 < 32; ++j2) {
                int j = q * 32 + ((j2 + q * 8) & 31);
                dot += res[j] * (double)c[j];
            }
            dot += __shfl_xor(dot, 16, 64);
            dot += __shfl_xor(dot, 32, 64);

            const float rc32 = (float)dot;
            const float t1 = rr32 - 2.0f * rc32;     // fp32 round
            const float d2 = t1 + s_cc32[g][k];      // fp32 round

            // first-min argmin over 16 codes (butterfly, tie -> smaller idx)
            float bv = d2; int bk = k;
            {
                float ov; int ok;
                ov = __shfl_xor(bv, 1, 64); ok = __shfl_xor(bk, 1, 64);
                if (ov < bv || (ov == bv && ok < bk)) { bv = ov; bk = ok; }
                ov = __shfl_xor(bv, 2, 64); ok = __shfl_xor(bk, 2, 64);
                if (ov < bv || (ov == bv && ok < bk)) { bv = ov; bk = ok; }
                ov = __shfl_xor(bv, 4, 64); ok = __shfl_xor(bk, 4, 64);
                if (ov < bv || (ov == bv && ok < bk)) { bv = ov; bk = ok; }
                ov = __shfl_xor(bv, 8, 64); ok = __shfl_xor(bk, 8, 64);
                if (ov < bv || (ov == bv && ok < bk)) { bv = ov; bk = ok; }
            }
            if (lane == 0)
                ids_out[(size_t)n * 9 + id_col0 + g] = (float)bk;

            res[lane]      -= (double)s_cb[(g * 16 + bk) * 129 + lane];
            res[lane + 64] -= (double)s_cb[(g * 16 + bk) * 129 + lane + 64];
        }
        double r0 = res[lane], r1 = res[lane + 64];
        double wl = r0 * r0 + r1 * r1;
        wl += __shfl_xor(wl, 1, 64);
        wl += __shfl_xor(wl, 2, 64);
        wl += __shfl_xor(wl, 4, 64);
        wl += __shfl_xor(wl, 8, 64);
        wl += __shfl_xor(wl, 16, 64);
        wl += __shfl_xor(wl, 32, 64);
        if (lane == 0) s_ws[w] = wl;
    }

    // ---- phase E (LAST only): linear head, wave w on its node ----
    if (LAST) {
        const int n = n0 + w;
        if (lane < OUT_C) {
            double acc = (double)lin_b[lane];
            for (int kk = 0; kk < HID; ++kk)
                acc += s_h[w][kk] * (double)lin_W[kk * OUT_C + lane];
            out[(size_t)n * OUT_C + lane] = (float)acc;
        }
    }

    __syncthreads();
    if (t == 0) {
        double s = 0.0;
#pragma unroll
        for (int i = 0; i < 8; i++) s += s_ws[i];
        loss_part[blockIdx.x] = s;
    }
}

// ---------------------------------------------------------------------------
__global__ __launch_bounds__(256)
void finalize_kernel(const double* __restrict__ loss_part, int M,
                     float* __restrict__ out_loss) {
    __shared__ double s[256];
    const int t = threadIdx.x;
    double v = 0.0;
    for (int i = t; i < M; i += 256) v += loss_part[i];
    s[t] = v;
    __syncthreads();
    for (int off = 128; off; off >>= 1) {
        if (t < off) s[t] += s[t + off];
        __syncthreads();
    }
    if (t == 0) out_loss[0] = (float)(s[0] / ((double)NN * (double)HID));
}

// ---------------------------------------------------------------------------
extern "C" void kernel_launch(void* const* d_in, const int* in_sizes, int n_in,
                              void* d_out, int out_size, void* d_ws, size_t ws_size,
                              hipStream_t stream) {
    const float* x    = (const float*)d_in[0];
    const int*   src  = (const int*)d_in[1];
    const int*   dst  = (const int*)d_in[2];
    const float* W0a = (const float*)d_in[3];
    const float* W0r = (const float*)d_in[4];
    const float* b0  = (const float*)d_in[5];
    const float* W1a = (const float*)d_in[6];
    const float* W1r = (const float*)d_in[7];
    const float* b1  = (const float*)d_in[8];
    const float* W2a = (const float*)d_in[9];
    const float* W2r = (const float*)d_in[10];
    const float* b2  = (const float*)d_in[11];
    const float* bn_gamma = (const float*)d_in[12];
    const float* bn_beta  = (const float*)d_in[13];
    const float* bn_mean  = (const float*)d_in[14];
    const float* bn_var   = (const float*)d_in[15];
    const float* cb    = (const float*)d_in[16];
    const float* lin_W = (const float*)d_in[17];
    const float* lin_b = (const float*)d_in[18];

    const int E = in_sizes[1];

    float* out      = (float*)d_out;                    // [N*40]
    float* out_loss = out + (size_t)NN * OUT_C;         // [1]
    float* out_ids  = out_loss + 1;                     // [N*9] as float

    // ---- workspace layout, 512B-aligned segments ----
    char* base = (char*)d_ws;
    size_t off = 0;
    auto alloc = [&](size_t bytes) -> void* {
        off = (off + 511) & ~(size_t)511;
        void* p = base + off;
        off += bytes;
        return p;
    };
    int* deg_i      = (int*)alloc((size_t)NN * 4);
    int* row_start  = (int*)alloc((size_t)(NN + 1) * 4);
    int* cursor     = (int*)alloc((size_t)NN * 4);
    int* csr_src    = (int*)alloc((size_t)E * 4);
    int* chunk_sums = (int*)alloc(256 * 4);
    double* loss_part = (double*)alloc((size_t)3 * 6250 * 8);
    double* h1 = (double*)alloc((size_t)NN * HID * 8);  // f64 h / agg (aliased)
    double* h2 = (double*)alloc((size_t)NN * HID * 8);

    const int cb_layer = 3 * 16 * HID;
    const int NB = NN / 8;                              // 6250 mlp blocks
    const int NA = NN / 4;                              // 12500 agg blocks
    const int NCHUNK = (NN + 255) / 256;                // 196

    // ---- CSR build ----
    hipMemsetAsync(deg_i, 0, NN * sizeof(int), stream);
    hist_kernel<<<(E + 255) / 256, 256, 0, stream>>>(dst, deg_i, E);
    chunk_sum_kernel<<<NCHUNK, 256, 0, stream>>>(deg_i, chunk_sums, NN);
    chunk_scan_kernel<<<1, 256, 0, stream>>>(chunk_sums, NCHUNK);
    chunk_apply_kernel<<<NCHUNK, 256, 0, stream>>>(deg_i, chunk_sums, row_start, cursor, NN);
    scatter_kernel<<<(E + 255) / 256, 256, 0, stream>>>(src, dst, cursor, csr_src, E);

    // ---- layer 0: agg(x) -> h1 region; mlp reads agg(h1), writes h(h1) ----
    agg_kernel<IN_C, float><<<NA, 256, 0, stream>>>(x, row_start, csr_src, h1);
    mlp_rvq<IN_C, true, false, float><<<NB, 512, 0, stream>>>(
        x, h1, W0a, W0r, b0, bn_gamma, bn_beta, bn_mean, bn_var,
        cb + 0 * cb_layer, h1, out_ids, 0, loss_part, nullptr, nullptr, nullptr);

    // ---- layer 1: agg(h1) -> h2 region; mlp reads agg(h2), writes h(h2) ----
    agg_kernel<HID, double><<<NA, 256, 0, stream>>>(h1, row_start, csr_src, h2);
    mlp_rvq<HID, true, false, double><<<NB, 512, 0, stream>>>(
        h1, h2, W1a, W1r, b1,
        bn_gamma + HID, bn_beta + HID, bn_mean + HID, bn_var + HID,
        cb + 1 * cb_layer, h2, out_ids, 3, loss_part + NB, nullptr, nullptr, nullptr);

    // ---- layer 2: agg(h2) -> h1 region (h1 dead); mlp LAST (no h_out) ----
    agg_kernel<HID, double><<<NA, 256, 0, stream>>>(h2, row_start, csr_src, h1);
    mlp_rvq<HID, false, true, double><<<NB, 512, 0, stream>>>(
        h2, h1, W2a, W2r, b2, nullptr, nullptr, nullptr, nullptr,
        cb + 2 * cb_layer, nullptr, out_ids, 6, loss_part + 2 * NB, lin_W, lin_b, out);

    // ---- loss ----
    finalize_kernel<<<1, 256, 0, stream>>>(loss_part, 3 * NB, out_loss);
}

// Round 17
// 1010.112 us; speedup vs baseline: 1.0927x; 1.0927x over previous
//
#include <hip/hip_runtime.h>

#define NN 50000
#define HID 128
#define IN_C 100
#define OUT_C 40

// ---------------------------------------------------------------------------
__global__ __launch_bounds__(256)
void hist_kernel(const int* __restrict__ dst, int* __restrict__ deg, int E) {
    int e = blockIdx.x * 256 + threadIdx.x;
    if (e < E) atomicAdd(&deg[dst[e]], 1);
}

// ---------------------------------------------------------------------------
__global__ __launch_bounds__(256)
void chunk_sum_kernel(const int* __restrict__ deg, int* __restrict__ chunk_sums, int N) {
    __shared__ int s[256];
    const int t = threadIdx.x;
    const int i = blockIdx.x * 256 + t;
    s[t] = (i < N) ? deg[i] : 0;
    __syncthreads();
    for (int o = 128; o; o >>= 1) { if (t < o) s[t] += s[t + o]; __syncthreads(); }
    if (t == 0) chunk_sums[blockIdx.x] = s[0];
}

__global__ __launch_bounds__(256)
void chunk_scan_kernel(int* __restrict__ chunk_sums, int M) {
    __shared__ int s[256];
    const int t = threadIdx.x;
    int v = (t < M) ? chunk_sums[t] : 0;
    s[t] = v;
    __syncthreads();
    for (int o = 1; o < 256; o <<= 1) {
        int x = (t >= o) ? s[t - o] : 0;
        __syncthreads();
        s[t] += x;
        __syncthreads();
    }
    if (t < M) chunk_sums[t] = s[t] - v;   // exclusive
}

__global__ __launch_bounds__(256)
void chunk_apply_kernel(const int* __restrict__ deg, const int* __restrict__ chunk_sums,
                        int* __restrict__ row_start, int* __restrict__ cursor, int N) {
    __shared__ int s[256];
    const int t = threadIdx.x;
    const int i = blockIdx.x * 256 + t;
    int v = (i < N) ? deg[i] : 0;
    s[t] = v;
    __syncthreads();
    for (int o = 1; o < 256; o <<= 1) {
        int x = (t >= o) ? s[t - o] : 0;
        __syncthreads();
        s[t] += x;
        __syncthreads();
    }
    if (i < N) {
        int ex = chunk_sums[blockIdx.x] + s[t] - v;
        row_start[i] = ex;
        cursor[i] = ex;
        if (i == N - 1) row_start[N] = ex + v;
    }
}

// ---------------------------------------------------------------------------
__global__ __launch_bounds__(256)
void scatter_kernel(const int* __restrict__ src, const int* __restrict__ dst,
                    int* __restrict__ cursor, int* __restrict__ csr_src, int E) {
    int e = blockIdx.x * 256 + threadIdx.x;
    if (e < E) {
        int pos = atomicAdd(&cursor[dst[e]], 1);
        csr_src[pos] = src[e];
    }
}

// ---------------------------------------------------------------------------
// pack {Wa[k][col], Wr[k][col]} as f64 double2 -> single b128 load in GEMM,
// no per-iteration v_cvt_f64_f32. Values exact (f32->f64 widening).
__global__ __launch_bounds__(128)
void prep_wpack(const float* __restrict__ Wa, const float* __restrict__ Wr,
                double2* __restrict__ wp) {
    const int k = blockIdx.x, col = threadIdx.x;
    wp[(size_t)k * HID + col] =
        make_double2((double)Wa[(size_t)k * HID + col],
                     (double)Wr[(size_t)k * HID + col]);
}

// ---------------------------------------------------------------------------
__device__ __forceinline__ double2 ld2(const double* p) {
    return *(const double2*)p;
}
__device__ __forceinline__ double2 ld2(const float* p) {
    float2 v = *(const float2*)p;
    return make_double2((double)v.x, (double)v.y);
}

// ---------------------------------------------------------------------------
// GOLDEN layer kernel (r15, 953us total) with ONE change: GEMM reads
// pre-packed f64 {wa,wr} (1 x b128 load/iter) instead of 2 f32 loads + 2
// v_cvt_f64_f32. Issue per iter ~30 -> ~21 cyc. (512,6) kept: r7 showed
// (512,8)'s VGPR-32 cap causes scratch spills (+350MB phantom HBM traffic).
// Numerics recipe (DO NOT CHANGE): f64 h end-to-end; all accumulation f64;
// d2 = fl32(fl32(rr32 - 2*rc32) + cc32); argmin = first-min.
template<int K, bool HAS_BN, bool LAST, typename TIN>
__global__ __launch_bounds__(512, 6)
void layer_fused(const TIN* __restrict__ h_in,
                 const int* __restrict__ row_start, const int* __restrict__ csr_src,
                 const double2* __restrict__ wp, const float* __restrict__ b,
                 const float* __restrict__ gamma, const float* __restrict__ beta,
                 const float* __restrict__ mean, const float* __restrict__ var,
                 const float* __restrict__ cb,       // [3*16*128] this layer
                 double* __restrict__ h_out,
                 float* __restrict__ ids_out, int id_col0,
                 double* __restrict__ loss_part,
                 const float* __restrict__ lin_W, const float* __restrict__ lin_b,
                 float* __restrict__ out) {
    __shared__ double s_agg[8][HID];   // phase A: agg; phase C/D: h rows (rvq res)
    __shared__ double s_h[8][HID];     // root rows; LAST: output rows for head
    __shared__ float s_cb[3 * 16 * 129];   // padded stride 129
    __shared__ float s_cc32[3][16];
    __shared__ double s_ws[8];
    const int t = threadIdx.x;
    const int w = t >> 6, lane = t & 63;
    const int n0 = blockIdx.x * 8;

    // ---- codebook -> LDS (padded) ----
    for (int idx = t; idx < 3 * 16 * 128; idx += 512)
        s_cb[(idx >> 7) * 129 + (idx & 127)] = cb[idx];

    // ---- phase A: wave w gathers node n0+w; lane covers features 2l, 2l+1 ----
    {
        const int n = n0 + w;
        const int r0 = row_start[n], r1 = row_start[n + 1];
        const int f0 = 2 * lane;
        if (f0 < K) {
            double s0 = 0, s1 = 0, s2 = 0, s3 = 0, s4 = 0, s5 = 0, s6 = 0, s7 = 0;
            int i = r0;
            for (; i + 3 < r1; i += 4) {
                const double2 v0 = ld2(h_in + (size_t)csr_src[i] * K + f0);
                const double2 v1 = ld2(h_in + (size_t)csr_src[i + 1] * K + f0);
                const double2 v2 = ld2(h_in + (size_t)csr_src[i + 2] * K + f0);
                const double2 v3 = ld2(h_in + (size_t)csr_src[i + 3] * K + f0);
                s0 += v0.x; s1 += v0.y; s2 += v1.x; s3 += v1.y;
                s4 += v2.x; s5 += v2.y; s6 += v3.x; s7 += v3.y;
            }
            for (; i < r1; ++i) {
                const double2 v = ld2(h_in + (size_t)csr_src[i] * K + f0);
                s0 += v.x; s1 += v.y;
            }
            const int deg = r1 - r0;
            const double dd = (double)(deg > 1 ? deg : 1);
            const double2 root = ld2(h_in + (size_t)n * K + f0);
            s_agg[w][f0]     = ((s0 + s2) + (s4 + s6)) / dd;
            s_agg[w][f0 + 1] = ((s1 + s3) + (s5 + s7)) / dd;
            s_h[w][f0]     = root.x;
            s_h[w][f0 + 1] = root.y;
        }
    }
    __syncthreads();

    // ---- phase B: GEMM, packed f64 weights (1 b128 load/iter), f64 FMA ----
    const int col = t & 127;
    const int p4 = t >> 7;      // 0..3; nodes p4 and p4+4
    double accA = (double)b[col];
    double accB = accA;
#pragma unroll 4
    for (int k = 0; k < K; ++k) {
        const double2 wv = wp[(size_t)k * HID + col];
        accA += s_agg[p4][k] * wv.x + s_h[p4][k] * wv.y;
        accB += s_agg[p4 + 4][k] * wv.x + s_h[p4 + 4][k] * wv.y;
    }
    __syncthreads();   // all GEMM reads of s_agg/s_h complete

    // ---- phase C: BN(f64)+ReLU, write f64 h, stash rows for RVQ (and head) ----
    {
        double vA = accA, vB = accB;
        if (HAS_BN) {
            const double scale = (double)gamma[col] / sqrt((double)var[col] + 1e-5);
            const double shift = (double)beta[col] - (double)mean[col] * scale;
            vA = vA * scale + shift; vA = vA > 0.0 ? vA : 0.0;
            vB = vB * scale + shift; vB = vB > 0.0 ? vB : 0.0;
        }
        h_out[(size_t)(n0 + p4) * HID + col] = vA;
        h_out[(size_t)(n0 + p4 + 4) * HID + col] = vB;
        s_agg[p4][col] = vA;
        s_agg[p4 + 4][col] = vB;
        if (LAST) {                      // keep output rows for the linear head
            s_h[p4][col] = vA;
            s_h[p4 + 4][col] = vB;
        }
    }
    if (t < 48) {
        const float* c = &s_cb[t * 129];
        double s = 0.0;
        for (int j = 0; j < 128; j++) { double cj = (double)c[j]; s += cj * cj; }
        s_cc32[t >> 4][t & 15] = (float)s;
    }
    __syncthreads();

    // ---- phase D: RVQ, wave w on its node (wave-lockstep, no barriers) ----
    {
        double* res = &s_agg[w][0];
        const int n = n0 + w;
        const int k = lane & 15, q = lane >> 4;

        for (int g = 0; g < 3; ++g) {
            // rr = ||res||^2 (f64 butterfly)
            double r0 = res[lane], r1 = res[lane + 64];
            double pr = r0 * r0 + r1 * r1;
            pr += __shfl_xor(pr, 1, 64);
            pr += __shfl_xor(pr, 2, 64);
            pr += __shfl_xor(pr, 4, 64);
            pr += __shfl_xor(pr, 8, 64);
            pr += __shfl_xor(pr, 16, 64);
            pr += __shfl_xor(pr, 32, 64);
            const float rr32 = (float)pr;

            // dot(res, c_k): lane (k,q) does quarter q with q-rotation
            const float* c = &s_cb[(g * 16 + k) * 129];
            double dot = 0.0;
#pragma unroll
            for (int j2 = 0; j2 < 32; ++j2) {
                int j = q * 32 + ((j2 + q * 8) & 31);
                dot += res[j] * (double)c[j];
            }
            dot += __shfl_xor(dot, 16, 64);
            dot += __shfl_xor(dot, 32, 64);

            const float rc32 = (float)dot;
            const float t1 = rr32 - 2.0f * rc32;     // fp32 round
            const float d2 = t1 + s_cc32[g][k];      // fp32 round

            // first-min argmin over 16 codes (butterfly, tie -> smaller idx)
            float bv = d2; int bk = k;
            {
                float ov; int ok;
                ov = __shfl_xor(bv, 1, 64); ok = __shfl_xor(bk, 1, 64);
                if (ov < bv || (ov == bv && ok < bk)) { bv = ov; bk = ok; }
                ov = __shfl_xor(bv, 2, 64); ok = __shfl_xor(bk, 2, 64);
                if (ov < bv || (ov == bv && ok < bk)) { bv = ov; bk = ok; }
                ov = __shfl_xor(bv, 4, 64); ok = __shfl_xor(bk, 4, 64);
                if (ov < bv || (ov == bv && ok < bk)) { bv = ov; bk = ok; }
                ov = __shfl_xor(bv, 8, 64); ok = __shfl_xor(bk, 8, 64);
                if (ov < bv || (ov == bv && ok < bk)) { bv = ov; bk = ok; }
            }
            if (lane == 0)
                ids_out[(size_t)n * 9 + id_col0 + g] = (float)bk;

            res[lane]      -= (double)s_cb[(g * 16 + bk) * 129 + lane];
            res[lane + 64] -= (double)s_cb[(g * 16 + bk) * 129 + lane + 64];
        }
        double r0 = res[lane], r1 = res[lane + 64];
        double wl = r0 * r0 + r1 * r1;
        wl += __shfl_xor(wl, 1, 64);
        wl += __shfl_xor(wl, 2, 64);
        wl += __shfl_xor(wl, 4, 64);
        wl += __shfl_xor(wl, 8, 64);
        wl += __shfl_xor(wl, 16, 64);
        wl += __shfl_xor(wl, 32, 64);
        if (lane == 0) s_ws[w] = wl;
    }

    // ---- phase E (LAST only): linear head, wave w on its node ----
    if (LAST) {
        const int n = n0 + w;
        if (lane < OUT_C) {
            double acc = (double)lin_b[lane];
            for (int kk = 0; kk < HID; ++kk)
                acc += s_h[w][kk] * (double)lin_W[kk * OUT_C + lane];
            out[(size_t)n * OUT_C + lane] = (float)acc;
        }
    }

    __syncthreads();
    if (t == 0) {
        double s = 0.0;
#pragma unroll
        for (int i = 0; i < 8; i++) s += s_ws[i];
        loss_part[blockIdx.x] = s;
    }
}

// ---------------------------------------------------------------------------
__global__ __launch_bounds__(256)
void finalize_kernel(const double* __restrict__ loss_part, int M,
                     float* __restrict__ out_loss) {
    __shared__ double s[256];
    const int t = threadIdx.x;
    double v = 0.0;
    for (int i = t; i < M; i += 256) v += loss_part[i];
    s[t] = v;
    __syncthreads();
    for (int off = 128; off; off >>= 1) {
        if (t < off) s[t] += s[t + off];
        __syncthreads();
    }
    if (t == 0) out_loss[0] = (float)(s[0] / ((double)NN * (double)HID));
}

// ---------------------------------------------------------------------------
extern "C" void kernel_launch(void* const* d_in, const int* in_sizes, int n_in,
                              void* d_out, int out_size, void* d_ws, size_t ws_size,
                              hipStream_t stream) {
    const float* x    = (const float*)d_in[0];
    const int*   src  = (const int*)d_in[1];
    const int*   dst  = (const int*)d_in[2];
    const float* W0a = (const float*)d_in[3];
    const float* W0r = (const float*)d_in[4];
    const float* b0  = (const float*)d_in[5];
    const float* W1a = (const float*)d_in[6];
    const float* W1r = (const float*)d_in[7];
    const float* b1  = (const float*)d_in[8];
    const float* W2a = (const float*)d_in[9];
    const float* W2r = (const float*)d_in[10];
    const float* b2  = (const float*)d_in[11];
    const float* bn_gamma = (const float*)d_in[12];
    const float* bn_beta  = (const float*)d_in[13];
    const float* bn_mean  = (const float*)d_in[14];
    const float* bn_var   = (const float*)d_in[15];
    const float* cb    = (const float*)d_in[16];
    const float* lin_W = (const float*)d_in[17];
    const float* lin_b = (const float*)d_in[18];

    const int E = in_sizes[1];

    float* out      = (float*)d_out;                    // [N*40]
    float* out_loss = out + (size_t)NN * OUT_C;         // [1]
    float* out_ids  = out_loss + 1;                     // [N*9] as float

    // ---- workspace layout, 512B-aligned segments ----
    char* base = (char*)d_ws;
    size_t off = 0;
    auto alloc = [&](size_t bytes) -> void* {
        off = (off + 511) & ~(size_t)511;
        void* p = base + off;
        off += bytes;
        return p;
    };
    int* deg_i      = (int*)alloc((size_t)NN * 4);
    int* row_start  = (int*)alloc((size_t)(NN + 1) * 4);
    int* cursor     = (int*)alloc((size_t)NN * 4);
    int* csr_src    = (int*)alloc((size_t)E * 4);
    int* chunk_sums = (int*)alloc(256 * 4);
    double* loss_part = (double*)alloc((size_t)3 * 6250 * 8);
    double* h1 = (double*)alloc((size_t)NN * HID * 8);  // f64 h
    double* h2 = (double*)alloc((size_t)NN * HID * 8);
    double2* wp0 = (double2*)alloc((size_t)IN_C * HID * 16);
    double2* wp1 = (double2*)alloc((size_t)HID * HID * 16);
    double2* wp2 = (double2*)alloc((size_t)HID * HID * 16);

    const int cb_layer = 3 * 16 * HID;
    const int NB = NN / 8;                              // 6250 blocks
    const int NCHUNK = (NN + 255) / 256;                // 196

    // ---- CSR build ----
    hipMemsetAsync(deg_i, 0, NN * sizeof(int), stream);
    hist_kernel<<<(E + 255) / 256, 256, 0, stream>>>(dst, deg_i, E);
    chunk_sum_kernel<<<NCHUNK, 256, 0, stream>>>(deg_i, chunk_sums, NN);
    chunk_scan_kernel<<<1, 256, 0, stream>>>(chunk_sums, NCHUNK);
    chunk_apply_kernel<<<NCHUNK, 256, 0, stream>>>(deg_i, chunk_sums, row_start, cursor, NN);
    scatter_kernel<<<(E + 255) / 256, 256, 0, stream>>>(src, dst, cursor, csr_src, E);

    // ---- weight packing (f64 double2) ----
    prep_wpack<<<IN_C, 128, 0, stream>>>(W0a, W0r, wp0);
    prep_wpack<<<HID, 128, 0, stream>>>(W1a, W1r, wp1);
    prep_wpack<<<HID, 128, 0, stream>>>(W2a, W2r, wp2);

    // ---- fused layers ----
    layer_fused<IN_C, true, false, float><<<NB, 512, 0, stream>>>(
        x, row_start, csr_src, wp0, b0, bn_gamma, bn_beta, bn_mean, bn_var,
        cb + 0 * cb_layer, h1, out_ids, 0, loss_part, nullptr, nullptr, nullptr);

    layer_fused<HID, true, false, double><<<NB, 512, 0, stream>>>(
        h1, row_start, csr_src, wp1, b1,
        bn_gamma + HID, bn_beta + HID, bn_mean + HID, bn_var + HID,
        cb + 1 * cb_layer, h2, out_ids, 3, loss_part + NB, nullptr, nullptr, nullptr);

    layer_fused<HID, false, true, double><<<NB, 512, 0, stream>>>(
        h2, row_start, csr_src, wp2, b2, nullptr, nullptr, nullptr, nullptr,
        cb + 2 * cb_layer, h1, out_ids, 6, loss_part + 2 * NB, lin_W, lin_b, out);

    // ---- loss ----
    finalize_kernel<<<1, 256, 0, stream>>>(loss_part, 3 * NB, out_loss);
}